// Round 9
// baseline (12815.404 us; speedup 1.0000x reference)
//
#include <hip/hip_runtime.h>

// Problem constants
#define BB 128
#define TT 512
#define HH 512
#define K4H 2048
#define KTOT 1024   // combined K: k<512 -> h@Wh, k>=512 -> x@Wx

typedef short bfrag  __attribute__((ext_vector_type(8)));   // 8 bf16 (4 VGPRs)
typedef float facc   __attribute__((ext_vector_type(16)));  // 16 f32 acc
typedef unsigned short u16;
typedef unsigned short ushortx8 __attribute__((ext_vector_type(8)));
typedef unsigned long long u64;
typedef unsigned int u32;

__device__ __forceinline__ u16 f2bf(float x){
    unsigned u = __builtin_bit_cast(unsigned, x);
    unsigned r = (u + 0x7fffu + ((u >> 16) & 1u)) >> 16;   // RNE
    return (u16)r;
}
__device__ __forceinline__ float bf2f(u16 h){
    unsigned u = ((unsigned)h) << 16;
    return __builtin_bit_cast(float, u);
}
__device__ __forceinline__ float fast_tanh(float x){
    float e = __expf(2.f * x);
    return 1.f - 2.f * __builtin_amdgcn_rcpf(e + 1.f);
}
__device__ __forceinline__ float fast_sig(float x){
    return __builtin_amdgcn_rcpf(1.f + __expf(-x));
}

// ---- prep: X -> bf16 hi/lo split ----
__global__ void prep_x(const float* __restrict__ X, u16* __restrict__ Xhi, u16* __restrict__ Xlo){
    size_t g = (size_t)blockIdx.x * blockDim.x + threadIdx.x;   // one float4 per thread
    float4 v = ((const float4*)X)[g];
    u16 h0 = f2bf(v.x), h1 = f2bf(v.y), h2 = f2bf(v.z), h3 = f2bf(v.w);
    ushort4 hh; hh.x = h0; hh.y = h1; hh.z = h2; hh.w = h3;
    ushort4 ll;
    ll.x = f2bf(v.x - bf2f(h0)); ll.y = f2bf(v.y - bf2f(h1));
    ll.z = f2bf(v.z - bf2f(h2)); ll.w = f2bf(v.w - bf2f(h3));
    ((ushort4*)Xhi)[g] = hh;
    ((ushort4*)Xlo)[g] = ll;
}

// ---- prep: transpose+split weights into WT[c][k], k = [Wh rows | Wx rows] ----
__global__ void prep_w(const float* __restrict__ Wx, const float* __restrict__ Wh,
                       u16* __restrict__ WThi, u16* __restrict__ WTlo){
    int c = blockIdx.x;  // 0..2047
    for (int kk = threadIdx.x; kk < KTOT; kk += blockDim.x){
        float w = (kk < 512) ? Wh[(size_t)kk * K4H + c] : Wx[(size_t)(kk - 512) * K4H + c];
        u16 hi = f2bf(w);
        u16 lo = f2bf(w - bf2f(hi));
        WThi[(size_t)c * KTOT + kk] = hi;
        WTlo[(size_t)c * KTOT + kk] = lo;
    }
}

// ---- prep: zero h buf0, barrier slots, and out row t=0 ----
__global__ void prep_misc(u16* __restrict__ hH, u16* __restrict__ hL,
                          u32* __restrict__ cbar, float* __restrict__ out){
    int i = blockIdx.x * blockDim.x + threadIdx.x;   // 65536 threads
    hH[i] = 0; hL[i] = 0;
    if (i < 256) cbar[i] = 0;
    int b = i >> 9, j = i & 511;
    out[(size_t)b * (TT * HH) + j] = 0.f;            // out[b][0][j]
}

// 3-product split-bf16 MFMA (hi*hi + hi*lo + lo*hi)
#define MF3(ACC, AH, AL, BH, BL) \
    ACC = __builtin_amdgcn_mfma_f32_32x32x16_bf16(AH, BH, ACC, 0, 0, 0); \
    ACC = __builtin_amdgcn_mfma_f32_32x32x16_bf16(AH, BL, ACC, 0, 0, 0); \
    ACC = __builtin_amdgcn_mfma_f32_32x32x16_bf16(AL, BH, ACC, 0, 0, 0);

// ---- main cooperative kernel: 64 WGs x 1024 thr (16 waves), 511 steps ----
// Same verified R2/R8 sync semantics (sc1 h stores -> syncthreads -> RELEASE flag;
// consumers: relaxed poll + ONE agent-acquire fence per WG per step + cached loads),
// but 4x fewer WGs: each WG = 4 column-groups (cg) x 4 K-split waves.
//   - barrier groups: 16 WGs (straggler max over 16, not 64)
//   - fences: 64/step machine-wide (was 256) -- R6 measured ~0.9us per extra fence
//   - post-fence h re-read amplification: 16x (4 MB/step, was 16 MB)
// Per-wave code identical to R2 (112-VGPR class). launch_bounds(1024,1) caps VGPR
// at 128 so 4 waves/SIMD always fit (R3-R7 lesson: geometry/resource failures give
// an all-zero timeout signature -- keep resources provably within limits).
__global__ void __launch_bounds__(1024, 1) lstm_main(
    const u16* __restrict__ Xhi, const u16* __restrict__ Xlo,
    const u16* __restrict__ WThi, const u16* __restrict__ WTlo,
    const float* __restrict__ bias,
    u16* __restrict__ hH, u16* __restrict__ hL,
    u32* __restrict__ cbar,
    float* __restrict__ out)
{
    __shared__ float red[4][4][32][36];   // [cg][kh][batch][32 cols + pad] = 73.7 KB

    const int tid  = threadIdx.x;
    const int lane = tid & 63;
    const int w    = tid >> 6;         // wave id 0..15
    const int cg   = w >> 2;           // column-group 0..3
    const int kh   = w & 3;            // K-split index 0..3
    const int wid  = blockIdx.x;
    const int bt   = wid & 3;          // batch tile (32 batches) == barrier group
    const int jb   = wid >> 2;         // j-block 0..15; WG covers h-idx jb*32..jb*32+31

    const int n  = lane & 31;          // MFMA row/col within tile
    const int kg = (lane >> 5) * 8;    // k sub-group

    // effective js (8-h-index set) for this wave's column tile: same formula as R2
    const int js_eff = jb * 4 + cg;    // 0..63
    const int c_n = (n >> 3) * 512 + js_eff * 8 + (n & 7);
    const size_t wrow = (size_t)c_n * KTOT;

#define LDB(NH, NL, KK) \
    bfrag NH = __builtin_bit_cast(bfrag, *(const ushortx8*)(WThi + wrow + (KK))); \
    bfrag NL = __builtin_bit_cast(bfrag, *(const ushortx8*)(WTlo + wrow + (KK)));

    LDB(bh0, bl0, kh*128 + 0*16 + kg)      // h-part weights
    LDB(bh1, bl1, kh*128 + 1*16 + kg)
    LDB(bh2, bl2, kh*128 + 2*16 + kg)
    LDB(bh3, bl3, kh*128 + 3*16 + kg)
    LDB(bh4, bl4, kh*128 + 4*16 + kg)
    LDB(bh5, bl5, kh*128 + 5*16 + kg)
    LDB(bh6, bl6, kh*128 + 6*16 + kg)
    LDB(bh7, bl7, kh*128 + 7*16 + kg)
    LDB(cx0, dx0, 512 + kh*128 + 0*16 + kg)  // x-part weights
    LDB(cx1, dx1, 512 + kh*128 + 1*16 + kg)
    LDB(cx2, dx2, 512 + kh*128 + 2*16 + kg)
    LDB(cx3, dx3, 512 + kh*128 + 3*16 + kg)
    LDB(cx4, dx4, 512 + kh*128 + 4*16 + kg)
    LDB(cx5, dx5, 512 + kh*128 + 5*16 + kg)
    LDB(cx6, dx6, 512 + kh*128 + 6*16 + kg)
    LDB(cx7, dx7, 512 + kh*128 + 7*16 + kg)

    // A-fragment addressing (row m = n lane field)
    const int bgm = bt * 32 + n;                        // global batch row for A
    const size_t xrow = (size_t)bgm * (TT * 512);       // + t*512 + k
    const int xk    = kh * 128 + kg;
    const int hbase = bgm * 512 + kh * 128 + kg;

    // gate threads: tid<512, each owns (batch, 2 adjacent j) within one cg
    const int blt  = tid >> 4;           // 0..31 batch local (tid<512)
    const int pidx = tid & 15;           // 16 j-pairs: cg' = pidx>>2, jp = (pidx&3)*2
    const int cgg  = pidx >> 2;
    const int jp   = (pidx & 3) * 2;
    const int bg   = bt * 32 + blt;
    const int jg0  = jb * 32 + cgg * 8 + jp;
    float biasr[8];
    if (tid < 512){
#pragma unroll
        for (int g = 0; g < 4; g++){
            biasr[2*g]   = bias[g * 512 + jg0];
            biasr[2*g+1] = bias[g * 512 + jg0 + 1];
        }
    }

    float cs0 = 0.f, cs1 = 0.f;
    facc acc0 = {0.f,0.f,0.f,0.f,0.f,0.f,0.f,0.f,0.f,0.f,0.f,0.f,0.f,0.f,0.f,0.f};
    facc acc1 = {0.f,0.f,0.f,0.f,0.f,0.f,0.f,0.f,0.f,0.f,0.f,0.f,0.f,0.f,0.f,0.f};

#define XSTEP(I, ACC, BH, BL) do{ \
    bfrag ah = __builtin_bit_cast(bfrag, *(const ushortx8*)(xh + I*16)); \
    bfrag al = __builtin_bit_cast(bfrag, *(const ushortx8*)(xl + I*16)); \
    MF3(ACC, ah, al, BH, BL) }while(0)

// Plain L1/L2-cached vector loads; coherence guaranteed by the per-step acquire fence.
#define HSTEP(I, ACC, BH, BL) do{ \
    bfrag ah = __builtin_bit_cast(bfrag, *(const ushortx8*)(hhp + I*16)); \
    bfrag al = __builtin_bit_cast(bfrag, *(const ushortx8*)(hlp + I*16)); \
    MF3(ACC, ah, al, BH, BL) }while(0)

    // This WG's arrival slot; wave 0 polls the 16 group slots (lane&15).
    u32* const myslot   = cbar + bt * 16 + jb;
    const u32* const pollslot = cbar + bt * 16 + (lane & 15);

    for (int t = 0; t < 511; t++){
        // ---- x-part GEMM (independent of h): issue BEFORE barrier spin ----
        const u16* xh = Xhi + xrow + (size_t)t * 512 + xk;
        const u16* xl = Xlo + xrow + (size_t)t * 512 + xk;
        XSTEP(0, acc0, cx0, dx0);
        XSTEP(1, acc1, cx1, dx1);
        XSTEP(2, acc0, cx2, dx2);
        XSTEP(3, acc1, cx3, dx3);
        XSTEP(4, acc0, cx4, dx4);
        XSTEP(5, acc1, cx5, dx5);
        XSTEP(6, acc0, cx6, dx6);
        XSTEP(7, acc1, cx7, dx7);

        // ---- group barrier: wait until all 16 WGs of this bt published h_t ----
        if (t){
            if (tid < 64){
                const u32 tgt = (u32)t;
                bool ok;
                do {
                    u32 c = __hip_atomic_load(pollslot, __ATOMIC_RELAXED,
                                              __HIP_MEMORY_SCOPE_AGENT);
                    ok = (bool)__all((int)(c >= tgt));
                    if (!ok) __builtin_amdgcn_s_sleep(2);
                } while (!ok);
                // ONE agent-acquire fence per WG per step (vL1+L2 invalidate) so the
                // plain h loads below observe the IC-resident h_t.
                __builtin_amdgcn_fence(__ATOMIC_ACQUIRE, "agent");
            }
            __syncthreads();
        }

        // ---- h-part GEMM (plain loads; L2-cached, cg-waves share lines via L1) ----
        const u16* hhp = hH + (size_t)(t & 1) * (BB * 512) + hbase;
        const u16* hlp = hL + (size_t)(t & 1) * (BB * 512) + hbase;
        HSTEP(0, acc0, bh0, bl0);
        HSTEP(1, acc1, bh1, bl1);
        HSTEP(2, acc0, bh2, bl2);
        HSTEP(3, acc1, bh3, bl3);
        HSTEP(4, acc0, bh4, bl4);
        HSTEP(5, acc1, bh5, bl5);
        HSTEP(6, acc0, bh6, bl6);
        HSTEP(7, acc1, bh7, bl7);

        // ---- split-K reduction via LDS ----
#pragma unroll
        for (int r = 0; r < 16; r++){
            int mrow = (r & 3) + 8 * (r >> 2) + 4 * (lane >> 5);  // verified C layout
            red[cg][kh][mrow][n] = acc0[r] + acc1[r];
        }
#pragma unroll
        for (int r = 0; r < 16; r++){ acc0[r] = 0.f; acc1[r] = 0.f; }
        __syncthreads();   // (C) red visible to gate threads

        // ---- gates + state update: tid<512, 2 adjacent j each ----
        float hn0 = 0.f, hn1 = 0.f;
        if (tid < 512){
            float v0[4], v1[4];
#pragma unroll
            for (int g = 0; g < 4; g++){
                int nn = g * 8 + jp;
                v0[g] = red[cgg][0][blt][nn]   + red[cgg][1][blt][nn]   + red[cgg][2][blt][nn]   + red[cgg][3][blt][nn]   + biasr[2*g];
                v1[g] = red[cgg][0][blt][nn+1] + red[cgg][1][blt][nn+1] + red[cgg][2][blt][nn+1] + red[cgg][3][blt][nn+1] + biasr[2*g+1];
            }
            float f0 = fast_sig(fast_tanh(v0[0])), f1 = fast_sig(fast_tanh(v1[0]));
            float g0 = fast_tanh(fast_tanh(v0[1])), g1 = fast_tanh(fast_tanh(v1[1]));
            float i0 = fast_sig(fast_tanh(v0[2])), i1 = fast_sig(fast_tanh(v1[2]));
            float o0 = fast_sig(fast_tanh(v0[3])), o1 = fast_sig(fast_tanh(v1[3]));
            hn0 = o0 * fast_tanh(cs0);
            hn1 = o1 * fast_tanh(cs1);
            cs0 = f0 * cs0 + g0 * i0;
            cs1 = f1 * cs1 + g1 * i1;

            // h hi/lo: packed u32 agent-scope stores (write-through to IC)
            u16 h0i = f2bf(hn0), h1i = f2bf(hn1);
            u32 hpack = (u32)h0i | ((u32)h1i << 16);
            u16 l0i = f2bf(hn0 - bf2f(h0i)), l1i = f2bf(hn1 - bf2f(h1i));
            u32 lpack = (u32)l0i | ((u32)l1i << 16);
            size_t hidx = (size_t)((t + 1) & 1) * (BB * 512) + (size_t)bg * 512 + jg0;
            __hip_atomic_store((u32*)(hH + hidx), hpack, __ATOMIC_RELAXED, __HIP_MEMORY_SCOPE_AGENT);
            __hip_atomic_store((u32*)(hL + hidx), lpack, __ATOMIC_RELAXED, __HIP_MEMORY_SCOPE_AGENT);
        }

        __syncthreads();   // (A) all h stores issued before arrival
        // RELEASE required (R3-R5 lesson): orders sc1 h-store visibility before flag.
        if (tid == 0)
            __hip_atomic_store(myslot, (u32)(t + 1), __ATOMIC_RELEASE,
                               __HIP_MEMORY_SCOPE_AGENT);

        // out: after the flag so its IC ack is off the publish critical path.
        if (tid < 512){
            float2 ov; ov.x = hn0; ov.y = hn1;
            u64 opack = __builtin_bit_cast(u64, ov);
            __hip_atomic_store((u64*)(out + (size_t)bg * (TT * HH) + (size_t)(t + 1) * HH + jg0),
                               opack, __ATOMIC_RELAXED, __HIP_MEMORY_SCOPE_AGENT);
        }
    }
}

extern "C" void kernel_launch(void* const* d_in, const int* in_sizes, int n_in,
                              void* d_out, int out_size, void* d_ws, size_t ws_size,
                              hipStream_t stream)
{
    const float* X    = (const float*)d_in[0];
    const float* Wx   = (const float*)d_in[1];
    const float* Wh   = (const float*)d_in[2];
    const float* bias = (const float*)d_in[3];
    float* out = (float*)d_out;

    char* ws = (char*)d_ws;
    u16* Xhi  = (u16*)(ws);                      // 64 MiB
    u16* Xlo  = (u16*)(ws + 67108864ull);        // 64 MiB
    u16* WThi = (u16*)(ws + 134217728ull);       // 4 MiB
    u16* WTlo = (u16*)(ws + 138412032ull);       // 4 MiB
    u16* hHp  = (u16*)(ws + 142606336ull);       // 256 KiB (double buffered)
    u16* hLp  = (u16*)(ws + 142868480ull);       // 256 KiB
    u32* cbar = (u32*)(ws + 143130624ull);       // arrival slots (4 groups x 16)

    hipLaunchKernelGGL(prep_x,    dim3(32768), dim3(256), 0, stream, X, Xhi, Xlo);
    hipLaunchKernelGGL(prep_w,    dim3(2048),  dim3(256), 0, stream, Wx, Wh, WThi, WTlo);
    hipLaunchKernelGGL(prep_misc, dim3(256),   dim3(256), 0, stream, hHp, hLp, cbar, out);

    void* args[] = { (void*)&Xhi, (void*)&Xlo, (void*)&WThi, (void*)&WTlo,
                     (void*)&bias, (void*)&hHp, (void*)&hLp, (void*)&cbar, (void*)&out };
    hipLaunchCooperativeKernel(lstm_main, dim3(64), dim3(1024), args, 0, stream);
}

// Round 10
// 4814.317 us; speedup vs baseline: 2.6619x; 2.6619x over previous
//
#include <hip/hip_runtime.h>

// Problem constants
#define BB 128
#define TT 512
#define HH 512
#define K4H 2048
#define KTOT 1024   // combined K: k<512 -> h@Wh, k>=512 -> x@Wx

typedef short bfrag  __attribute__((ext_vector_type(8)));   // 8 bf16 (4 VGPRs)
typedef float facc   __attribute__((ext_vector_type(16)));  // 16 f32 acc
typedef unsigned short u16;
typedef unsigned short ushortx8 __attribute__((ext_vector_type(8)));
typedef unsigned long long u64;
typedef u64 u64x2 __attribute__((ext_vector_type(2)));
typedef unsigned int u32;

__device__ __forceinline__ u16 f2bf(float x){
    unsigned u = __builtin_bit_cast(unsigned, x);
    unsigned r = (u + 0x7fffu + ((u >> 16) & 1u)) >> 16;   // RNE
    return (u16)r;
}
__device__ __forceinline__ float bf2f(u16 h){
    unsigned u = ((unsigned)h) << 16;
    return __builtin_bit_cast(float, u);
}
__device__ __forceinline__ float fast_tanh(float x){
    float e = __expf(2.f * x);
    return 1.f - 2.f * __builtin_amdgcn_rcpf(e + 1.f);
}
__device__ __forceinline__ float fast_sig(float x){
    return __builtin_amdgcn_rcpf(1.f + __expf(-x));
}
__device__ __forceinline__ bfrag mkfrag(u64 a, u64 b){
    u64x2 v; v.x = a; v.y = b;
    return __builtin_bit_cast(bfrag, v);
}

// ---- prep: X -> bf16 hi/lo split ----
__global__ void prep_x(const float* __restrict__ X, u16* __restrict__ Xhi, u16* __restrict__ Xlo){
    size_t g = (size_t)blockIdx.x * blockDim.x + threadIdx.x;   // one float4 per thread
    float4 v = ((const float4*)X)[g];
    u16 h0 = f2bf(v.x), h1 = f2bf(v.y), h2 = f2bf(v.z), h3 = f2bf(v.w);
    ushort4 hh; hh.x = h0; hh.y = h1; hh.z = h2; hh.w = h3;
    ushort4 ll;
    ll.x = f2bf(v.x - bf2f(h0)); ll.y = f2bf(v.y - bf2f(h1));
    ll.z = f2bf(v.z - bf2f(h2)); ll.w = f2bf(v.w - bf2f(h3));
    ((ushort4*)Xhi)[g] = hh;
    ((ushort4*)Xlo)[g] = ll;
}

// ---- prep: transpose+split weights into WT[c][k], k = [Wh rows | Wx rows] ----
__global__ void prep_w(const float* __restrict__ Wx, const float* __restrict__ Wh,
                       u16* __restrict__ WThi, u16* __restrict__ WTlo){
    int c = blockIdx.x;  // 0..2047
    for (int kk = threadIdx.x; kk < KTOT; kk += blockDim.x){
        float w = (kk < 512) ? Wh[(size_t)kk * K4H + c] : Wx[(size_t)(kk - 512) * K4H + c];
        u16 hi = f2bf(w);
        u16 lo = f2bf(w - bf2f(hi));
        WThi[(size_t)c * KTOT + kk] = hi;
        WTlo[(size_t)c * KTOT + kk] = lo;
    }
}

// ---- prep: h buffers with parity tags, slots (unused), out row t=0 ----
// Tag: LSB of every stored bf16 (hi AND lo) = ((step)>>1)&1 of the h living there.
// buf0 = h_0 = zeros, tag 0 (t=0 expects parity (0>>1)&1 = 0 -> passes immediately).
// buf1 poisoned tag 1 (t=1 expects parity 0 -> consumers wait for real h_1).
// Occupants of a buffer alternate parity (h_t vs h_{t+2}) -> staleness detectable.
__global__ void prep_misc(u16* __restrict__ hH, u16* __restrict__ hL,
                          u32* __restrict__ cbar, float* __restrict__ out){
    int i = blockIdx.x * blockDim.x + threadIdx.x;   // 131072 threads (full dbuf)
    u16 ini = (i < 65536) ? (u16)0 : (u16)1;
    hH[i] = ini; hL[i] = ini;
    if (i < 256) cbar[i] = 0;
    if (i < 65536){
        int b = i >> 9, j = i & 511;
        out[(size_t)b * (TT * HH) + j] = 0.f;        // out[b][0][j]
    }
}

// 3-product split-bf16 MFMA (hi*hi + hi*lo + lo*hi)
#define MF3(ACC, AH, AL, BH, BL) \
    ACC = __builtin_amdgcn_mfma_f32_32x32x16_bf16(AH, BH, ACC, 0, 0, 0); \
    ACC = __builtin_amdgcn_mfma_f32_32x32x16_bf16(AH, BL, ACC, 0, 0, 0); \
    ACC = __builtin_amdgcn_mfma_f32_32x32x16_bf16(AL, BH, ACC, 0, 0, 0);

// ---- main cooperative kernel: 256 WGs x 256 thr (verified geometry), 511 steps ----
// v10: FLAG-FREE, FENCE-FREE exchange in the verified 112-VGPR register class.
// h is self-validating (parity tag in every bf16 LSB). Consumers acquire h via
// agent-scope u64 loads (R1-verified mechanism -> bypass L1/L2, no fence; X stays
// L2-cached) in QUARTERS of 8 u64 (16 VGPRs in flight, R1's register profile) with
// a wave-wide retry per quarter. Quarter 0's retry IS the barrier wait.
// WAR-safety (no flags needed): WG w writes h_{t+1} only after tag-reading ALL 512
// cols of h_t (4 waves cover full k-range = all 64 producers); each producer wrote
// its h_t slice only after its step-(t-1) reads of h_{t-1} completed (enforced
// in-WG: gates depend on red <- sync(C) <- all waves' MFMAs <- their h loads).
// So h_{t+1}'s overwrite of h_{t-1} is proven safe; progress by induction on t.
// End-of-loop __syncthreads guards the LDS `red` WAR (a fast wave whose k-slice
// excludes its own WG's columns could otherwise lap the gate threads' reads).
// VGPR class kept ~R1/R8 (R3/4/5/7 lesson: >~200 arch VGPRs at this config makes
// the cooperative launch fail SILENTLY -> all-zero output, absmax 0.699).
__global__ void __launch_bounds__(256, 1) lstm_main(
    const u16* __restrict__ Xhi, const u16* __restrict__ Xlo,
    const u16* __restrict__ WThi, const u16* __restrict__ WTlo,
    const float* __restrict__ bias,
    u16* __restrict__ hH, u16* __restrict__ hL,
    u32* __restrict__ cbar,
    float* __restrict__ out)
{
    __shared__ float red[4][32][36];   // pitch 36: <=2-way bank aliasing

    const int tid  = threadIdx.x;
    const int lane = tid & 63;
    const int kh   = tid >> 6;         // wave id = K-split index
    const int wid  = blockIdx.x;
    const int bt   = wid & 3;          // batch tile (32 batches)
    const int js   = wid >> 2;         // j-set (8 h-indices)

    const int n  = lane & 31;          // MFMA row/col within tile
    const int kg = (lane >> 5) * 8;    // k sub-group

    // B fragments: named scalars -> register-resident for all 511 steps
    const int c_n = (n >> 3) * 512 + js * 8 + (n & 7);   // global column for frag col n
    const size_t wrow = (size_t)c_n * KTOT;

#define LDB(NH, NL, KK) \
    bfrag NH = __builtin_bit_cast(bfrag, *(const ushortx8*)(WThi + wrow + (KK))); \
    bfrag NL = __builtin_bit_cast(bfrag, *(const ushortx8*)(WTlo + wrow + (KK)));

    LDB(bh0, bl0, kh*128 + 0*16 + kg)      // h-part weights
    LDB(bh1, bl1, kh*128 + 1*16 + kg)
    LDB(bh2, bl2, kh*128 + 2*16 + kg)
    LDB(bh3, bl3, kh*128 + 3*16 + kg)
    LDB(bh4, bl4, kh*128 + 4*16 + kg)
    LDB(bh5, bl5, kh*128 + 5*16 + kg)
    LDB(bh6, bl6, kh*128 + 6*16 + kg)
    LDB(bh7, bl7, kh*128 + 7*16 + kg)
    LDB(cx0, dx0, 512 + kh*128 + 0*16 + kg)  // x-part weights
    LDB(cx1, dx1, 512 + kh*128 + 1*16 + kg)
    LDB(cx2, dx2, 512 + kh*128 + 2*16 + kg)
    LDB(cx3, dx3, 512 + kh*128 + 3*16 + kg)
    LDB(cx4, dx4, 512 + kh*128 + 4*16 + kg)
    LDB(cx5, dx5, 512 + kh*128 + 5*16 + kg)
    LDB(cx6, dx6, 512 + kh*128 + 6*16 + kg)
    LDB(cx7, dx7, 512 + kh*128 + 7*16 + kg)

    // A-fragment addressing (row m = n lane field)
    const int bgm = bt * 32 + n;                        // global batch row for A
    const size_t xrow = (size_t)bgm * (TT * 512);       // + t*512 + k
    const int xk    = kh * 128 + kg;
    const int hbase = bgm * 512 + kh * 128 + kg;

    // gate threads: tid<128, each owns (batch, 2 adjacent j) so h stores are u32s
    const int blt = tid >> 2;            // 0..31 batch local (tid<128)
    const int jp  = (tid & 3) * 2;       // 0,2,4,6
    const int bg  = bt * 32 + blt;
    const int jg0 = js * 8 + jp;
    float biasr[8];
    if (tid < 128){
#pragma unroll
        for (int g = 0; g < 4; g++){
            biasr[2*g]   = bias[g * 512 + jg0];
            biasr[2*g+1] = bias[g * 512 + jg0 + 1];
        }
    }

    float cs0 = 0.f, cs1 = 0.f;
    facc acc0 = {0.f,0.f,0.f,0.f,0.f,0.f,0.f,0.f,0.f,0.f,0.f,0.f,0.f,0.f,0.f,0.f};
    facc acc1 = {0.f,0.f,0.f,0.f,0.f,0.f,0.f,0.f,0.f,0.f,0.f,0.f,0.f,0.f,0.f,0.f};

#define XSTEP(I, ACC, BH, BL) do{ \
    bfrag ah = __builtin_bit_cast(bfrag, *(const ushortx8*)(xh + I*16)); \
    bfrag al = __builtin_bit_cast(bfrag, *(const ushortx8*)(xl + I*16)); \
    MF3(ACC, ah, al, BH, BL) }while(0)

#define LDA(P) __hip_atomic_load((const u64*)(P), __ATOMIC_RELAXED, __HIP_MEMORY_SCOPE_AGENT)

    const u64 TAGM = 0x0001000100010001ull;

// Quarter = chunks 2Q,2Q+1 (8 u64 in flight). Retry until all 8 values carry the
// expected parity tag; consume straight into MFMAs. Q0's retry is the group wait.
#define HQUARTER(Q, BH0, BL0, BH1, BL1) do{ \
    const u64* ph0 = (const u64*)(hhp + (2*(Q))*16); \
    const u64* ph1 = (const u64*)(hhp + (2*(Q)+1)*16); \
    const u64* pl0 = (const u64*)(hlp + (2*(Q))*16); \
    const u64* pl1 = (const u64*)(hlp + (2*(Q)+1)*16); \
    u64 a0,a1,a2,a3,b0,b1,b2,b3; \
    for(;;){ \
        a0 = LDA(ph0); a1 = LDA(ph0+1); a2 = LDA(ph1); a3 = LDA(ph1+1); \
        b0 = LDA(pl0); b1 = LDA(pl0+1); b2 = LDA(pl1); b3 = LDA(pl1+1); \
        u64 m = (a0^par)|(a1^par)|(a2^par)|(a3^par) \
              | (b0^par)|(b1^par)|(b2^par)|(b3^par); \
        if (__all((int)((m & TAGM) == 0ull))) break; \
        __builtin_amdgcn_s_sleep(1); \
    } \
    MF3(acc0, mkfrag(a0,a1), mkfrag(b0,b1), BH0, BL0) \
    MF3(acc1, mkfrag(a2,a3), mkfrag(b2,b3), BH1, BL1) }while(0)

    for (int t = 0; t < 511; t++){
        // ---- x-part GEMM (independent of h; L2-cached -- no fences exist) ----
        const u16* xh = Xhi + xrow + (size_t)t * 512 + xk;
        const u16* xl = Xlo + xrow + (size_t)t * 512 + xk;
        XSTEP(0, acc0, cx0, dx0);
        XSTEP(1, acc1, cx1, dx1);
        XSTEP(2, acc0, cx2, dx2);
        XSTEP(3, acc1, cx3, dx3);
        XSTEP(4, acc0, cx4, dx4);
        XSTEP(5, acc1, cx5, dx5);
        XSTEP(6, acc0, cx6, dx6);
        XSTEP(7, acc1, cx7, dx7);

        // ---- tag-validated h acquisition + h-GEMM (one global hop total) ----
        const u16* hhp = hH + (size_t)(t & 1) * (BB * 512) + hbase;
        const u16* hlp = hL + (size_t)(t & 1) * (BB * 512) + hbase;
        const u64 par = ((t >> 1) & 1) ? TAGM : 0ull;
        HQUARTER(0, bh0, bl0, bh1, bl1);
        HQUARTER(1, bh2, bl2, bh3, bl3);
        HQUARTER(2, bh4, bl4, bh5, bl5);
        HQUARTER(3, bh6, bl6, bh7, bl7);

        // ---- split-K reduction via LDS ----
#pragma unroll
        for (int r = 0; r < 16; r++){
            int mrow = (r & 3) + 8 * (r >> 2) + 4 * (lane >> 5);  // verified C layout
            red[kh][mrow][n] = acc0[r] + acc1[r];
        }
#pragma unroll
        for (int r = 0; r < 16; r++){ acc0[r] = 0.f; acc1[r] = 0.f; }
        __syncthreads();   // (C) red visible to gates; also anchors the WAR proof

        // ---- gates + state update + tagged publish: tid<128 ----
        if (tid < 128){
            float v0[4], v1[4];
#pragma unroll
            for (int g = 0; g < 4; g++){
                int nn = g * 8 + jp;
                v0[g] = red[0][blt][nn]   + red[1][blt][nn]   + red[2][blt][nn]   + red[3][blt][nn]   + biasr[2*g];
                v1[g] = red[0][blt][nn+1] + red[1][blt][nn+1] + red[2][blt][nn+1] + red[3][blt][nn+1] + biasr[2*g+1];
            }
            float f0 = fast_sig(fast_tanh(v0[0])), f1 = fast_sig(fast_tanh(v1[0]));
            float g0 = fast_tanh(fast_tanh(v0[1])), g1 = fast_tanh(fast_tanh(v1[1]));
            float i0 = fast_sig(fast_tanh(v0[2])), i1 = fast_sig(fast_tanh(v1[2]));
            float o0 = fast_sig(fast_tanh(v0[3])), o1 = fast_sig(fast_tanh(v1[3]));
            float hn0 = o0 * fast_tanh(cs0);
            float hn1 = o1 * fast_tanh(cs1);
            cs0 = f0 * cs0 + g0 * i0;
            cs1 = f1 * cs1 + g1 * i1;

            // h hi/lo with parity tag in every bf16 LSB; lo absorbs hi's forced LSB
            // (residual ~2^-16 relative -- far under the absmax margin).
            u16 pb = (u16)(((t + 1) >> 1) & 1);
            u16 h0i = (u16)((f2bf(hn0) & 0xFFFEu) | pb);
            u16 h1i = (u16)((f2bf(hn1) & 0xFFFEu) | pb);
            u32 hpack = (u32)h0i | ((u32)h1i << 16);
            u16 l0i = (u16)((f2bf(hn0 - bf2f(h0i)) & 0xFFFEu) | pb);
            u16 l1i = (u16)((f2bf(hn1 - bf2f(h1i)) & 0xFFFEu) | pb);
            u32 lpack = (u32)l0i | ((u32)l1i << 16);
            size_t hidx = (size_t)((t + 1) & 1) * (BB * 512) + (size_t)bg * 512 + jg0;
            __hip_atomic_store((u32*)(hH + hidx), hpack, __ATOMIC_RELAXED, __HIP_MEMORY_SCOPE_AGENT);
            __hip_atomic_store((u32*)(hL + hidx), lpack, __ATOMIC_RELAXED, __HIP_MEMORY_SCOPE_AGENT);

            // out: after the h publish (off the recurrence path; drains at endpgm)
            float2 ov; ov.x = hn0; ov.y = hn1;
            u64 opack = __builtin_bit_cast(u64, ov);
            __hip_atomic_store((u64*)(out + (size_t)bg * (TT * HH) + (size_t)(t + 1) * HH + jg0),
                               opack, __ATOMIC_RELAXED, __HIP_MEMORY_SCOPE_AGENT);
        }

        __syncthreads();   // (D) LDS `red` WAR: no wave starts next reduce early
    }
}

extern "C" void kernel_launch(void* const* d_in, const int* in_sizes, int n_in,
                              void* d_out, int out_size, void* d_ws, size_t ws_size,
                              hipStream_t stream)
{
    const float* X    = (const float*)d_in[0];
    const float* Wx   = (const float*)d_in[1];
    const float* Wh   = (const float*)d_in[2];
    const float* bias = (const float*)d_in[3];
    float* out = (float*)d_out;

    char* ws = (char*)d_ws;
    u16* Xhi  = (u16*)(ws);                      // 64 MiB
    u16* Xlo  = (u16*)(ws + 67108864ull);        // 64 MiB
    u16* WThi = (u16*)(ws + 134217728ull);       // 4 MiB
    u16* WTlo = (u16*)(ws + 138412032ull);       // 4 MiB
    u16* hHp  = (u16*)(ws + 142606336ull);       // 256 KiB (double buffered)
    u16* hLp  = (u16*)(ws + 142868480ull);       // 256 KiB
    u32* cbar = (u32*)(ws + 143130624ull);       // 1 KiB (unused by v10, kept)

    hipLaunchKernelGGL(prep_x,    dim3(32768), dim3(256), 0, stream, X, Xhi, Xlo);
    hipLaunchKernelGGL(prep_w,    dim3(2048),  dim3(256), 0, stream, Wx, Wh, WThi, WTlo);
    hipLaunchKernelGGL(prep_misc, dim3(512),   dim3(256), 0, stream, hHp, hLp, cbar, out);

    void* args[] = { (void*)&Xhi, (void*)&Xlo, (void*)&WThi, (void*)&WTlo,
                     (void*)&bias, (void*)&hHp, (void*)&hLp, (void*)&cbar, (void*)&out };
    hipLaunchCooperativeKernel(lstm_main, dim3(256), dim3(256), args, 0, stream);
}